// Round 3
// baseline (1573.651 us; speedup 1.0000x reference)
//
#include <hip/hip_runtime.h>
#include <hip/hip_bf16.h>

// MoEFSCIL: B=16, H=W=16, L=256, DIM=768, NH=8, HD=96, NEXP=8, TOPK=2,
// DSTATE=1, DTRANK=4, KDIR=4. All inputs fp32; OUTPUT fp32 (16x768).
// Gate computed first so only the 32 selected (batch,expert) pairs run the
// expert path (4x less expert GEMM work).

#define LTOK 256
#define DIMC 768

// ---------------------------------------------------------------------------
// Generic batched fp32 GEMM: C[z](M,N) = A[z](M,K) @ op(B[z]) + bias
// bIsNT=1: B stored (N,K) row-major (C=A*B^T). bIsNT=0: B stored (K,N).
// Batch offsets: z1=z/zdiv, z2=z%zdiv, off = z1*s1 + z2*s2 per operand.
// pairExp non-null => MoE pair mode: e=pairExp[z]; A off=(z>>1)*sA1,
// B off=e*sB1, C off=z*sC1, bias off=e*sBias1.
// ---------------------------------------------------------------------------
__global__ __launch_bounds__(256) void mk_gemm(
    const float* __restrict__ A, const float* __restrict__ B,
    const float* __restrict__ bias, float* __restrict__ C,
    int M, int N, int K, int lda, int ldb, int ldc,
    int zdiv,
    long sA1, long sA2, long sB1, long sB2, long sC1, long sC2, long sBias1,
    int bIsNT, const int* __restrict__ pairExp, int tilesN)
{
  int z = blockIdx.y;
  long aoff, boff, coff, biasoff = 0;
  if (pairExp) {
    int e = pairExp[z];
    aoff = (long)(z >> 1) * sA1;
    boff = (long)e * sB1;
    coff = (long)z * sC1;
    biasoff = (long)e * sBias1;
  } else {
    int z1 = z / zdiv, z2 = z - z1 * zdiv;
    aoff = (long)z1 * sA1 + (long)z2 * sA2;
    boff = (long)z1 * sB1 + (long)z2 * sB2;
    coff = (long)z1 * sC1 + (long)z2 * sC2;
  }
  const float* Ab = A + aoff;
  const float* Bb = B + boff;
  float* Cb = C + coff;

  int tile = blockIdx.x;
  int tm = tile / tilesN, tn = tile - tm * tilesN;
  int m0 = tm << 6, n0 = tn << 6;

  __shared__ float As[16][68];
  __shared__ float Bs[16][68];

  int tid = threadIdx.x;
  int tx = tid & 15, ty = tid >> 4;
  int lrow = tid >> 2;            // 0..63
  int lk = (tid & 3) << 2;        // 0,4,8,12
  int bkk = tid >> 4;             // 0..15 (NN loader)
  int bnn = (tid & 15) << 2;      // 0..60

  float acc[4][4];
#pragma unroll
  for (int i = 0; i < 4; i++)
#pragma unroll
    for (int j = 0; j < 4; j++) acc[i][j] = 0.f;

  for (int k0 = 0; k0 < K; k0 += 16) {
    {
      int gm = m0 + lrow;
      float4 v = {0.f, 0.f, 0.f, 0.f};
      if (gm < M) v = *(const float4*)(Ab + (long)gm * lda + (k0 + lk));
      As[lk + 0][lrow] = v.x; As[lk + 1][lrow] = v.y;
      As[lk + 2][lrow] = v.z; As[lk + 3][lrow] = v.w;
    }
    if (bIsNT) {
      int gn = n0 + lrow;
      float4 v = {0.f, 0.f, 0.f, 0.f};
      if (gn < N) v = *(const float4*)(Bb + (long)gn * ldb + (k0 + lk));
      Bs[lk + 0][lrow] = v.x; Bs[lk + 1][lrow] = v.y;
      Bs[lk + 2][lrow] = v.z; Bs[lk + 3][lrow] = v.w;
    } else {
      int gn = n0 + bnn;
      float4 v = {0.f, 0.f, 0.f, 0.f};
      if (gn + 3 < N) {
        v = *(const float4*)(Bb + (long)(k0 + bkk) * ldb + gn);
      } else {
        float t0 = (gn + 0 < N) ? Bb[(long)(k0 + bkk) * ldb + gn + 0] : 0.f;
        float t1 = (gn + 1 < N) ? Bb[(long)(k0 + bkk) * ldb + gn + 1] : 0.f;
        float t2 = (gn + 2 < N) ? Bb[(long)(k0 + bkk) * ldb + gn + 2] : 0.f;
        float t3 = (gn + 3 < N) ? Bb[(long)(k0 + bkk) * ldb + gn + 3] : 0.f;
        v.x = t0; v.y = t1; v.z = t2; v.w = t3;
      }
      *(float4*)&Bs[bkk][bnn] = v;
    }
    __syncthreads();
#pragma unroll
    for (int kk = 0; kk < 16; kk++) {
      float4 a = *(const float4*)&As[kk][ty << 2];
      float4 b = *(const float4*)&Bs[kk][tx << 2];
      acc[0][0] += a.x * b.x; acc[0][1] += a.x * b.y; acc[0][2] += a.x * b.z; acc[0][3] += a.x * b.w;
      acc[1][0] += a.y * b.x; acc[1][1] += a.y * b.y; acc[1][2] += a.y * b.z; acc[1][3] += a.y * b.w;
      acc[2][0] += a.z * b.x; acc[2][1] += a.z * b.y; acc[2][2] += a.z * b.z; acc[2][3] += a.z * b.w;
      acc[3][0] += a.w * b.x; acc[3][1] += a.w * b.y; acc[3][2] += a.w * b.z; acc[3][3] += a.w * b.w;
    }
    __syncthreads();
  }

  const float* bp = bias ? (bias + biasoff) : nullptr;
#pragma unroll
  for (int i = 0; i < 4; i++) {
    int gm = m0 + (ty << 2) + i;
    if (gm >= M) continue;
#pragma unroll
    for (int j = 0; j < 4; j++) {
      int gn = n0 + (tx << 2) + j;
      if (gn >= N) continue;
      float v = acc[i][j];
      if (bp) v += bp[gn];
      Cb[(long)gm * ldc + gn] = v;
    }
  }
}

// ---------------------------------------------------------------------------
// Row softmax over 256 entries; folds the 1/sqrt(HD) scale:
// softmax(s*scale) = exp(scale*(s - max)) / sum. One wave per row.
// ---------------------------------------------------------------------------
__global__ __launch_bounds__(256) void mk_softmax(float* __restrict__ scores, float scale)
{
  int row = (blockIdx.x << 2) + (threadIdx.x >> 6);
  int lane = threadIdx.x & 63;
  float* p = scores + (long)row * 256 + (lane << 2);
  float4 v = *(const float4*)p;
  float m = fmaxf(fmaxf(v.x, v.y), fmaxf(v.z, v.w));
#pragma unroll
  for (int o = 32; o; o >>= 1) m = fmaxf(m, __shfl_xor(m, o, 64));
  v.x = expf(scale * (v.x - m));
  v.y = expf(scale * (v.y - m));
  v.z = expf(scale * (v.z - m));
  v.w = expf(scale * (v.w - m));
  float s = v.x + v.y + v.z + v.w;
#pragma unroll
  for (int o = 32; o; o >>= 1) s += __shfl_xor(s, o, 64);
  float r = 1.f / s;
  v.x *= r; v.y *= r; v.z *= r; v.w *= r;
  *(float4*)p = v;
}

// ---------------------------------------------------------------------------
// Gate: per batch b, aw[l,h,e] = softmax_e(q2[b,l,h,:].k2[e,h,:]*scale),
// g[e] = softmax_e(mean_{h,l} aw); top-2 -> (expert idx, softmax weight).
// ---------------------------------------------------------------------------
__global__ __launch_bounds__(256) void mk_gate(const float* __restrict__ q2,
                                               const float* __restrict__ k2,
                                               int* __restrict__ pe, float* __restrict__ pw)
{
  __shared__ float k2s[8 * DIMC];
  int b = blockIdx.x;
  for (int i = threadIdx.x; i < 8 * DIMC; i += 256) k2s[i] = k2[i];
  __syncthreads();
  const float scale = 0.10206207261596577f;  // 1/sqrt(96)
  int l = threadIdx.x;
  const float* qp = q2 + ((long)b * LTOK + l) * DIMC;
  float acc[8];
#pragma unroll
  for (int e = 0; e < 8; e++) acc[e] = 0.f;
  for (int h = 0; h < 8; h++) {
    float s[8];
    for (int e = 0; e < 8; e++) {
      const float* kp = &k2s[e * DIMC + h * 96];
      const float* qh = qp + h * 96;
      float sum = 0.f;
#pragma unroll 4
      for (int j = 0; j < 96; j += 4) {
        float4 qv = *(const float4*)(qh + j);
        sum += qv.x * kp[j] + qv.y * kp[j + 1] + qv.z * kp[j + 2] + qv.w * kp[j + 3];
      }
      s[e] = sum * scale;
    }
    float mx = s[0];
#pragma unroll
    for (int e = 1; e < 8; e++) mx = fmaxf(mx, s[e]);
    float se = 0.f;
#pragma unroll
    for (int e = 0; e < 8; e++) { s[e] = expf(s[e] - mx); se += s[e]; }
    float inv = 1.f / se;
#pragma unroll
    for (int e = 0; e < 8; e++) acc[e] += s[e] * inv;
  }
#pragma unroll
  for (int o = 32; o; o >>= 1)
#pragma unroll
    for (int e = 0; e < 8; e++) acc[e] += __shfl_xor(acc[e], o, 64);
  __shared__ float red[4][8];
  int wid = threadIdx.x >> 6, lane = threadIdx.x & 63;
  if (lane == 0)
    for (int e = 0; e < 8; e++) red[wid][e] = acc[e];
  __syncthreads();
  if (threadIdx.x == 0) {
    float g[8];
    for (int e = 0; e < 8; e++)
      g[e] = (red[0][e] + red[1][e] + red[2][e] + red[3][e]) * (1.f / (8.f * 256.f));
    float mx = g[0];
    for (int e = 1; e < 8; e++) mx = fmaxf(mx, g[e]);
    float se = 0.f;
    for (int e = 0; e < 8; e++) { g[e] = expf(g[e] - mx); se += g[e]; }
    for (int e = 0; e < 8; e++) g[e] /= se;
    int i0 = 0;
    for (int e = 1; e < 8; e++) if (g[e] > g[i0]) i0 = e;
    int i1 = (i0 == 0) ? 1 : 0;
    for (int e = 0; e < 8; e++) if (e != i0 && g[e] > g[i1]) i1 = e;
    float w0 = 1.f / (1.f + expf(g[i1] - g[i0]));  // softmax over top-2 gate probs
    pe[2 * b] = i0; pe[2 * b + 1] = i1;
    pw[2 * b] = w0; pw[2 * b + 1] = 1.f - w0;
  }
}

// ---------------------------------------------------------------------------
// Depthwise 3x3 conv (pad 1) + bias + SiLU over xz[:, :768] -> xc.
// Grid: (pair*256 + token); 768 threads = one channel each.
// ---------------------------------------------------------------------------
__global__ __launch_bounds__(768) void mk_conv(const float* __restrict__ xz,
                                               const float* __restrict__ cw,
                                               const float* __restrict__ cb,
                                               const int* __restrict__ pe,
                                               float* __restrict__ xc)
{
  int blk = blockIdx.x;
  int p = blk >> 8, t = blk & 255;
  int e = pe[p];
  int h = t >> 4, w = t & 15;
  int c = threadIdx.x;
  const float* wp = cw + ((long)e * DIMC + c) * 9;
  float acc = cb[e * DIMC + c];
#pragma unroll
  for (int dh = 0; dh < 3; dh++) {
    int hh = h + dh - 1;
    if (hh < 0 || hh > 15) continue;
#pragma unroll
    for (int dw = 0; dw < 3; dw++) {
      int ww = w + dw - 1;
      if (ww < 0 || ww > 15) continue;
      acc += xz[((long)p * LTOK + hh * 16 + ww) * 1536 + c] * wp[dh * 3 + dw];
    }
  }
  xc[((long)p * LTOK + t) * DIMC + c] = acc / (1.f + expf(-acc));
}

// token mapping: scan index s -> row-major token, per direction
__device__ __forceinline__ int tmap(int dir, int s) {
  if (dir == 0) return s;
  if (dir == 1) return 255 - s;
  if (dir == 2) return ((s & 15) << 4) | (s >> 4);
  int u = 255 - s;
  return ((u & 15) << 4) | (u >> 4);
}

// ---------------------------------------------------------------------------
// Selective scan, one block per (pair, direction), one thread per channel.
// Computes dbl = xc_seq @ xproj^T (6 cols: 4 dt-rank, B, C) into LDS, then the
// L=256 sequential recurrence; adds result (+ D*x) into y_acc at the mapped
// row-major token via atomicAdd (4 directions merge).
// ---------------------------------------------------------------------------
__global__ __launch_bounds__(768) void mk_scan(const float* __restrict__ xc,
                                               const float* __restrict__ xproj,
                                               const float* __restrict__ dtw,
                                               const float* __restrict__ dtb,
                                               const float* __restrict__ Alog,
                                               const float* __restrict__ Dp,
                                               const int* __restrict__ pe,
                                               float* __restrict__ yac)
{
  int p = blockIdx.x >> 2, dir = blockIdx.x & 3;
  int e = pe[p];
  __shared__ float dbl[256][6];
  const float* xcp = xc + (long)p * LTOK * DIMC;
  const float* xpw = xproj + (long)(e * 4 + dir) * 6 * DIMC;
  int tid = threadIdx.x;
#pragma unroll
  for (int it = 0; it < 2; it++) {
    int id = tid + it * 768;
    int j = id >> 8;        // 0..5
    int s = id & 255;
    const float* xr = xcp + (long)tmap(dir, s) * DIMC;
    const float* wr = xpw + j * DIMC;
    float sum = 0.f;
#pragma unroll 4
    for (int cc = 0; cc < DIMC; cc += 4) {
      float4 xv = *(const float4*)(xr + cc);
      float4 wv = *(const float4*)(wr + cc);
      sum += xv.x * wv.x + xv.y * wv.y + xv.z * wv.z + xv.w * wv.w;
    }
    dbl[s][j] = sum;
  }
  __syncthreads();

  int d = tid;
  long pb = (long)(e * 4 + dir) * DIMC + d;
  float4 wv = *(const float4*)(dtw + pb * 4);
  float bdt = dtb[pb];
  float Ad = -expf(Alog[pb]);
  float Dd = Dp[pb];
  float h = 0.f;
  for (int t = 0; t < 256; t++) {
    int m = tmap(dir, t);
    float xr = wv.x * dbl[t][0] + wv.y * dbl[t][1] + wv.z * dbl[t][2] + wv.w * dbl[t][3] + bdt;
    float dt = fmaxf(xr, 0.f) + log1pf(expf(-fabsf(xr)));  // stable softplus
    float xv2 = xcp[(long)m * DIMC + d];
    h = expf(dt * Ad) * h + (dt * xv2) * dbl[t][4];
    atomicAdd(&yac[((long)p * LTOK + m) * DIMC + d], h * dbl[t][5] + Dd * xv2);
  }
}

// ---------------------------------------------------------------------------
// LayerNorm + *silu(z) + mean over tokens -> eo[pair][768].
// 12 waves; each wave owns tokens t = wid, wid+12, ... (full 768-ch row).
// ---------------------------------------------------------------------------
__global__ __launch_bounds__(768) void mk_lnfin(const float* __restrict__ yac,
                                                const float* __restrict__ xz,
                                                const float* __restrict__ lns,
                                                const float* __restrict__ lnb,
                                                const int* __restrict__ pe,
                                                float* __restrict__ eo)
{
  int p = blockIdx.x;
  int e = pe[p];
  int tid = threadIdx.x;
  int wid = tid >> 6, lane = tid & 63;
  float ls[12], lb[12], acc[12];
#pragma unroll
  for (int i = 0; i < 12; i++) {
    int d = i * 64 + lane;
    ls[i] = lns[e * DIMC + d];
    lb[i] = lnb[e * DIMC + d];
    acc[i] = 0.f;
  }
  for (int t = wid; t < 256; t += 12) {
    const float* yr = yac + ((long)p * LTOK + t) * DIMC;
    const float* zr = xz + ((long)p * LTOK + t) * 1536 + DIMC;
    float v[12];
    float s = 0.f;
#pragma unroll
    for (int i = 0; i < 12; i++) { v[i] = yr[i * 64 + lane]; s += v[i]; }
#pragma unroll
    for (int o = 32; o; o >>= 1) s += __shfl_xor(s, o, 64);
    float mu = s * (1.f / 768.f);
    float sq = 0.f;
#pragma unroll
    for (int i = 0; i < 12; i++) { float dlt = v[i] - mu; sq += dlt * dlt; }
#pragma unroll
    for (int o = 32; o; o >>= 1) sq += __shfl_xor(sq, o, 64);
    float rs = rsqrtf(sq * (1.f / 768.f) + 1e-5f);
#pragma unroll
    for (int i = 0; i < 12; i++) {
      float y = (v[i] - mu) * rs * ls[i] + lb[i];
      float z = zr[i * 64 + lane];
      y *= z / (1.f + expf(-z));
      acc[i] += y;
    }
  }
  __shared__ float sacc[768];
  sacc[tid] = 0.f;
  __syncthreads();
#pragma unroll
  for (int i = 0; i < 12; i++) atomicAdd(&sacc[i * 64 + lane], acc[i]);
  __syncthreads();
  eo[(long)p * DIMC + tid] = sacc[tid] * (1.f / 256.f);
}

// out[b] = w0*eo[2b] + w1*eo[2b+1]  (fp32 output!)
__global__ __launch_bounds__(768) void mk_out(const float* __restrict__ eo,
                                              const float* __restrict__ pw,
                                              float* __restrict__ out)
{
  int b = blockIdx.x, d = threadIdx.x;
  float v = pw[2 * b] * eo[(long)(2 * b) * DIMC + d] +
            pw[2 * b + 1] * eo[(long)(2 * b + 1) * DIMC + d];
  out[b * DIMC + d] = v;
}

// ---------------------------------------------------------------------------
static inline void launch_gemm(hipStream_t stream, const float* A, const float* B,
                               const float* bias, float* C,
                               int M, int N, int K, int lda, int ldb, int ldc,
                               int Z, int zdiv,
                               long sA1, long sA2, long sB1, long sB2,
                               long sC1, long sC2, long sBias1,
                               int bIsNT, const int* pairExp)
{
  int tilesM = (M + 63) >> 6, tilesN = (N + 63) >> 6;
  mk_gemm<<<dim3(tilesM * tilesN, Z), 256, 0, stream>>>(
      A, B, bias, C, M, N, K, lda, ldb, ldc, zdiv,
      sA1, sA2, sB1, sB2, sC1, sC2, sBias1, bIsNT, pairExp, tilesN);
}

extern "C" void kernel_launch(void* const* d_in, const int* in_sizes, int n_in,
                              void* d_out, int out_size, void* d_ws, size_t ws_size,
                              hipStream_t stream)
{
  const float* x        = (const float*)d_in[0];
  const float* sa_in_w  = (const float*)d_in[1];
  const float* sa_in_b  = (const float*)d_in[2];
  const float* sa_out_w = (const float*)d_in[3];
  const float* sa_out_b = (const float*)d_in[4];
  const float* ca_in_w  = (const float*)d_in[5];
  const float* ca_in_b  = (const float*)d_in[6];
  const float* eq       = (const float*)d_in[7];
  const float* e_in_w   = (const float*)d_in[8];
  const float* e_in_b   = (const float*)d_in[9];
  const float* e_conv_w = (const float*)d_in[10];
  const float* e_conv_b = (const float*)d_in[11];
  const float* e_xproj  = (const float*)d_in[12];
  const float* e_dtw    = (const float*)d_in[13];
  const float* e_dtb    = (const float*)d_in[14];
  const float* e_Alog   = (const float*)d_in[15];
  const float* e_D      = (const float*)d_in[16];
  const float* e_lns    = (const float*)d_in[17];
  const float* e_lnb    = (const float*)d_in[18];
  float* out = (float*)d_out;  // fp32 output per reference dtype

  float* ws = (float*)d_ws;
  // attention phase
  float* qkv    = ws + 0;          // 4096x2304        = 9,437,184
  float* scores = ws + 9437184;    // 16x8x256x256     = 8,388,608
  float* ctxa   = ws + 17825792;   // 4096x768         = 3,145,728 (ends 20,971,520)
  float* ctx    = ws + 9437184;    // reuse scores region
  float* q2     = ws + 12582912;   // 4096x768 (ends 15,728,640)
  // expert phase (reuses attention regions; all dead after gate)
  float* xz     = ws + 0;          // 32x256x1536      = 12,582,912
  float* xc     = ws + 12582912;   // 32x256x768       =  6,291,456 (ends 18,874,368)
  float* yac    = ws + 18874368;   // 32x256x768       =  6,291,456 (ends 25,165,824)
  // persistent small region (never overlapped)
  float* k2     = ws + 25165824;   // 8x768
  int*   pe     = (int*)(ws + 25171968);   // 32 expert ids
  float* pw     = ws + 25172000;   // 32 weights
  float* eo     = ws + 25172032;   // 32x768 (ends 25,196,608 floats = 100.8 MB)

  const float scale = 0.10206207261596577f;

  // 1. qkv = x @ sa_in_w^T + b           (4096 x 2304 x 768)
  launch_gemm(stream, x, sa_in_w, sa_in_b, qkv, 4096, 2304, 768, 768, 768, 2304,
              1, 1, 0, 0, 0, 0, 0, 0, 0, 1, nullptr);
  // 2. scores[b,h] = q @ k^T             (256 x 256 x 96, Z = 128)
  launch_gemm(stream, qkv, qkv + 768, nullptr, scores, 256, 256, 96, 2304, 2304, 256,
              128, 8, 589824, 96, 589824, 96, 524288, 65536, 0, 1, nullptr);
  // 3. softmax rows (scale folded)
  mk_softmax<<<8192, 256, 0, stream>>>(scores, scale);
  // 4. ctx_attn[b,h] = att @ v           (256 x 96 x 256, NN, Z = 128)
  launch_gemm(stream, scores, qkv + 1536, nullptr, ctxa, 256, 96, 256, 256, 2304, 768,
              128, 8, 524288, 65536, 589824, 96, 196608, 96, 0, 0, nullptr);
  // 5. ctx = ctx_attn @ sa_out_w^T + b   (4096 x 768 x 768)
  launch_gemm(stream, ctxa, sa_out_w, sa_out_b, ctx, 4096, 768, 768, 768, 768, 768,
              1, 1, 0, 0, 0, 0, 0, 0, 0, 1, nullptr);
  // 6. q2 = ctx @ ca_in_w[:768]^T + b
  launch_gemm(stream, ctx, ca_in_w, ca_in_b, q2, 4096, 768, 768, 768, 768, 768,
              1, 1, 0, 0, 0, 0, 0, 0, 0, 1, nullptr);
  // 7. k2 = eq @ ca_in_w[768:]^T + b     (8 x 768 x 768)
  launch_gemm(stream, eq, ca_in_w + 768 * 768, ca_in_b + 768, k2, 8, 768, 768, 768, 768, 768,
              1, 1, 0, 0, 0, 0, 0, 0, 0, 1, nullptr);
  // 8. gate -> top-2 (expert, weight) per batch
  mk_gate<<<16, 256, 0, stream>>>(q2, k2, pe, pw);
  // 9. xz[p] = x[b] @ e_in_w[e]^T + b    (256 x 1536 x 768, Z = 32 pairs)
  launch_gemm(stream, x, e_in_w, e_in_b, xz, 256, 1536, 768, 768, 768, 1536,
              32, 1, 196608, 0, 1179648, 0, 393216, 0, 1536, 1, pe);
  // 10. depthwise conv + SiLU
  mk_conv<<<32 * 256, 768, 0, stream>>>(xz, e_conv_w, e_conv_b, pe, xc);
  // 11. zero accumulator, 12. selective scans (4 dirs merge via atomicAdd)
  hipMemsetAsync(yac, 0, (size_t)6291456 * sizeof(float), stream);
  mk_scan<<<128, 768, 0, stream>>>(xc, e_xproj, e_dtw, e_dtb, e_Alog, e_D, pe, yac);
  // 13. LN + silu(z) gate + token mean
  mk_lnfin<<<32, 768, 0, stream>>>(yac, xz, e_lns, e_lnb, pe, eo);
  // 14. weighted top-2 combine -> fp32 out
  mk_out<<<16, 768, 0, stream>>>(eo, pw, out);

  (void)in_sizes; (void)n_in; (void)out_size; (void)ws_size;
}

// Round 4
// 929.080 us; speedup vs baseline: 1.6938x; 1.6938x over previous
//
#include <hip/hip_runtime.h>
#include <hip/hip_bf16.h>

// MoEFSCIL: B=16, H=W=16, L=256, DIM=768, NH=8, HD=96, NEXP=8, TOPK=2.
// fp32 in/out. Big GEMMs in bf16 MFMA (16x16x32), attention + scan fp32.

#define LTOK 256
#define DIMC 768

typedef unsigned short ushortt;
typedef __attribute__((ext_vector_type(8))) short bf16x8;
typedef __attribute__((ext_vector_type(4))) float f32x4;

// round-to-nearest-even fp32 -> bf16 bits
__device__ __forceinline__ ushortt f2b(float f) {
  union { float f; unsigned u; } c; c.f = f;
  unsigned r = (c.u + 0x7FFFu + ((c.u >> 16) & 1u)) >> 16;
  return (ushortt)r;
}

// ---------------------------------------------------------------------------
// fp32 -> bf16 cast, 4 elems/thread. n must be multiple of 4.
// ---------------------------------------------------------------------------
__global__ __launch_bounds__(256) void mk_cast(const float* __restrict__ in,
                                               ushortt* __restrict__ outp, long n)
{
  long i = ((long)blockIdx.x * 256 + threadIdx.x) * 4;
  if (i + 3 < n) {
    float4 v = *(const float4*)(in + i);
    ushort4 o;
    o.x = f2b(v.x); o.y = f2b(v.y); o.z = f2b(v.z); o.w = f2b(v.w);
    *(ushort4*)(outp + i) = o;
  }
}

// ---------------------------------------------------------------------------
// bf16 MFMA GEMM: C[z](M,N) = A[z](M,K) @ B[z](N,K)^T + bias. fp32 out.
// M,N multiples of 128; K multiple of 32. 128x128 tile, 4 waves of 64x64.
// pairExp non-null => MoE mode: e=pairExp[z]; aoff=(z>>1)*sA, boff=e*sB,
// coff=z*sC, biasoff=e*sBias. Otherwise single matrix (gridDim.y==1).
// ---------------------------------------------------------------------------
__global__ __launch_bounds__(256) void mk_mfma(
    const ushortt* __restrict__ A, const ushortt* __restrict__ B,
    const float* __restrict__ bias, float* __restrict__ C,
    int K, int lda, int ldb, int ldc,
    long sA, long sB, long sC, long sBias,
    const int* __restrict__ pairExp, int tilesN)
{
  int z = blockIdx.y;
  long aoff = 0, boff = 0, coff = 0, biasoff = 0;
  if (pairExp) {
    int e = pairExp[z];
    aoff = (long)(z >> 1) * sA; boff = (long)e * sB;
    coff = (long)z * sC; biasoff = (long)e * sBias;
  }
  int tile = blockIdx.x;
  int tm = tile / tilesN, tn = tile - tm * tilesN;
  long m0 = (long)tm << 7, n0 = (long)tn << 7;

  __shared__ ushortt As[128][40];  // stride 40 (80B): rows r,r+8 2-way (free)
  __shared__ ushortt Bs[128][40];

  int tid = threadIdx.x;
  int lane = tid & 63, wvi = tid >> 6;
  int wr = wvi >> 1, wc = wvi & 1;
  int lm = lane & 15, lg = lane >> 4;

  f32x4 zero4 = {0.f, 0.f, 0.f, 0.f};
  f32x4 acc[4][4];
#pragma unroll
  for (int i = 0; i < 4; i++)
#pragma unroll
    for (int j = 0; j < 4; j++) acc[i][j] = zero4;

  const ushortt* Ab = A + aoff;
  const ushortt* Bb = B + boff;

  for (int k0 = 0; k0 < K; k0 += 32) {
#pragma unroll
    for (int h = 0; h < 2; h++) {
      int q = tid + h * 256;           // 512 chunks = 128 rows x 4 x 8 elems
      int row = q >> 2, ck = (q & 3) << 3;
      *(uint4*)&As[row][ck] = *(const uint4*)(Ab + (m0 + row) * lda + k0 + ck);
      *(uint4*)&Bs[row][ck] = *(const uint4*)(Bb + (n0 + row) * ldb + k0 + ck);
    }
    __syncthreads();
    bf16x8 af[4], bfr[4];
#pragma unroll
    for (int i = 0; i < 4; i++)
      af[i] = *(const bf16x8*)&As[wr * 64 + i * 16 + lm][lg << 3];
#pragma unroll
    for (int j = 0; j < 4; j++)
      bfr[j] = *(const bf16x8*)&Bs[wc * 64 + j * 16 + lm][lg << 3];
#pragma unroll
    for (int i = 0; i < 4; i++)
#pragma unroll
      for (int j = 0; j < 4; j++)
        acc[i][j] = __builtin_amdgcn_mfma_f32_16x16x32_bf16(af[i], bfr[j], acc[i][j], 0, 0, 0);
    __syncthreads();
  }

#pragma unroll
  for (int mt = 0; mt < 4; mt++) {
#pragma unroll
    for (int nt = 0; nt < 4; nt++) {
      long grow = m0 + wr * 64 + mt * 16 + lg * 4;
      long gcol = n0 + wc * 64 + nt * 16 + lm;
      float bv = bias ? bias[biasoff + gcol] : 0.f;
#pragma unroll
      for (int r = 0; r < 4; r++)
        C[coff + (grow + r) * ldc + gcol] = acc[mt][nt][r] + bv;
    }
  }
}

// ---------------------------------------------------------------------------
// fp32 batched GEMM (attention + k2): C[z](M,N) = A[z](M,K) @ op(B[z]) + bias
// ---------------------------------------------------------------------------
__global__ __launch_bounds__(256) void mk_gemm(
    const float* __restrict__ A, const float* __restrict__ B,
    const float* __restrict__ bias, float* __restrict__ C,
    int M, int N, int K, int lda, int ldb, int ldc,
    int zdiv,
    long sA1, long sA2, long sB1, long sB2, long sC1, long sC2,
    int bIsNT, int tilesN)
{
  int z = blockIdx.y;
  int z1 = z / zdiv, z2 = z - z1 * zdiv;
  const float* Ab = A + (long)z1 * sA1 + (long)z2 * sA2;
  const float* Bb = B + (long)z1 * sB1 + (long)z2 * sB2;
  float* Cb = C + (long)z1 * sC1 + (long)z2 * sC2;

  int tile = blockIdx.x;
  int tm = tile / tilesN, tn = tile - tm * tilesN;
  int m0 = tm << 6, n0 = tn << 6;

  __shared__ float As[16][68];
  __shared__ float Bs[16][68];

  int tid = threadIdx.x;
  int tx = tid & 15, ty = tid >> 4;
  int lrow = tid >> 2;
  int lk = (tid & 3) << 2;
  int bkk = tid >> 4;
  int bnn = (tid & 15) << 2;

  float acc[4][4];
#pragma unroll
  for (int i = 0; i < 4; i++)
#pragma unroll
    for (int j = 0; j < 4; j++) acc[i][j] = 0.f;

  for (int k0 = 0; k0 < K; k0 += 16) {
    {
      int gm = m0 + lrow;
      float4 v = {0.f, 0.f, 0.f, 0.f};
      if (gm < M) v = *(const float4*)(Ab + (long)gm * lda + (k0 + lk));
      As[lk + 0][lrow] = v.x; As[lk + 1][lrow] = v.y;
      As[lk + 2][lrow] = v.z; As[lk + 3][lrow] = v.w;
    }
    if (bIsNT) {
      int gn = n0 + lrow;
      float4 v = {0.f, 0.f, 0.f, 0.f};
      if (gn < N) v = *(const float4*)(Bb + (long)gn * ldb + (k0 + lk));
      Bs[lk + 0][lrow] = v.x; Bs[lk + 1][lrow] = v.y;
      Bs[lk + 2][lrow] = v.z; Bs[lk + 3][lrow] = v.w;
    } else {
      int gn = n0 + bnn;
      float4 v = {0.f, 0.f, 0.f, 0.f};
      if (gn + 3 < N) {
        v = *(const float4*)(Bb + (long)(k0 + bkk) * ldb + gn);
      } else {
        float t0 = (gn + 0 < N) ? Bb[(long)(k0 + bkk) * ldb + gn + 0] : 0.f;
        float t1 = (gn + 1 < N) ? Bb[(long)(k0 + bkk) * ldb + gn + 1] : 0.f;
        float t2 = (gn + 2 < N) ? Bb[(long)(k0 + bkk) * ldb + gn + 2] : 0.f;
        float t3 = (gn + 3 < N) ? Bb[(long)(k0 + bkk) * ldb + gn + 3] : 0.f;
        v.x = t0; v.y = t1; v.z = t2; v.w = t3;
      }
      *(float4*)&Bs[bkk][bnn] = v;
    }
    __syncthreads();
#pragma unroll
    for (int kk = 0; kk < 16; kk++) {
      float4 a = *(const float4*)&As[kk][ty << 2];
      float4 b = *(const float4*)&Bs[kk][tx << 2];
      acc[0][0] += a.x * b.x; acc[0][1] += a.x * b.y; acc[0][2] += a.x * b.z; acc[0][3] += a.x * b.w;
      acc[1][0] += a.y * b.x; acc[1][1] += a.y * b.y; acc[1][2] += a.y * b.z; acc[1][3] += a.y * b.w;
      acc[2][0] += a.z * b.x; acc[2][1] += a.z * b.y; acc[2][2] += a.z * b.z; acc[2][3] += a.z * b.w;
      acc[3][0] += a.w * b.x; acc[3][1] += a.w * b.y; acc[3][2] += a.w * b.z; acc[3][3] += a.w * b.w;
    }
    __syncthreads();
  }

#pragma unroll
  for (int i = 0; i < 4; i++) {
    int gm = m0 + (ty << 2) + i;
    if (gm >= M) continue;
#pragma unroll
    for (int j = 0; j < 4; j++) {
      int gn = n0 + (tx << 2) + j;
      if (gn >= N) continue;
      float v = acc[i][j];
      if (bias) v += bias[gn];
      Cb[(long)gm * ldc + gn] = v;
    }
  }
}

// ---------------------------------------------------------------------------
__global__ __launch_bounds__(256) void mk_softmax(float* __restrict__ scores, float scale)
{
  int row = (blockIdx.x << 2) + (threadIdx.x >> 6);
  int lane = threadIdx.x & 63;
  float* p = scores + (long)row * 256 + (lane << 2);
  float4 v = *(const float4*)p;
  float m = fmaxf(fmaxf(v.x, v.y), fmaxf(v.z, v.w));
#pragma unroll
  for (int o = 32; o; o >>= 1) m = fmaxf(m, __shfl_xor(m, o, 64));
  v.x = expf(scale * (v.x - m));
  v.y = expf(scale * (v.y - m));
  v.z = expf(scale * (v.z - m));
  v.w = expf(scale * (v.w - m));
  float s = v.x + v.y + v.z + v.w;
#pragma unroll
  for (int o = 32; o; o >>= 1) s += __shfl_xor(s, o, 64);
  float r = 1.f / s;
  v.x *= r; v.y *= r; v.z *= r; v.w *= r;
  *(float4*)p = v;
}

// ---------------------------------------------------------------------------
__global__ __launch_bounds__(256) void mk_gate(const float* __restrict__ q2,
                                               const float* __restrict__ k2,
                                               int* __restrict__ pe, float* __restrict__ pw)
{
  __shared__ float k2s[8 * DIMC];
  int b = blockIdx.x;
  for (int i = threadIdx.x; i < 8 * DIMC; i += 256) k2s[i] = k2[i];
  __syncthreads();
  const float scale = 0.10206207261596577f;  // 1/sqrt(96)
  int l = threadIdx.x;
  const float* qp = q2 + ((long)b * LTOK + l) * DIMC;
  float acc[8];
#pragma unroll
  for (int e = 0; e < 8; e++) acc[e] = 0.f;
  for (int h = 0; h < 8; h++) {
    float s[8];
    for (int e = 0; e < 8; e++) {
      const float* kp = &k2s[e * DIMC + h * 96];
      const float* qh = qp + h * 96;
      float sum = 0.f;
#pragma unroll 4
      for (int j = 0; j < 96; j += 4) {
        float4 qv = *(const float4*)(qh + j);
        sum += qv.x * kp[j] + qv.y * kp[j + 1] + qv.z * kp[j + 2] + qv.w * kp[j + 3];
      }
      s[e] = sum * scale;
    }
    float mx = s[0];
#pragma unroll
    for (int e = 1; e < 8; e++) mx = fmaxf(mx, s[e]);
    float se = 0.f;
#pragma unroll
    for (int e = 0; e < 8; e++) { s[e] = expf(s[e] - mx); se += s[e]; }
    float inv = 1.f / se;
#pragma unroll
    for (int e = 0; e < 8; e++) acc[e] += s[e] * inv;
  }
#pragma unroll
  for (int o = 32; o; o >>= 1)
#pragma unroll
    for (int e = 0; e < 8; e++) acc[e] += __shfl_xor(acc[e], o, 64);
  __shared__ float red[4][8];
  int wid = threadIdx.x >> 6, lane = threadIdx.x & 63;
  if (lane == 0)
    for (int e = 0; e < 8; e++) red[wid][e] = acc[e];
  __syncthreads();
  if (threadIdx.x == 0) {
    float g[8];
    for (int e = 0; e < 8; e++)
      g[e] = (red[0][e] + red[1][e] + red[2][e] + red[3][e]) * (1.f / (8.f * 256.f));
    float mx = g[0];
    for (int e = 1; e < 8; e++) mx = fmaxf(mx, g[e]);
    float se = 0.f;
    for (int e = 0; e < 8; e++) { g[e] = expf(g[e] - mx); se += g[e]; }
    for (int e = 0; e < 8; e++) g[e] /= se;
    int i0 = 0;
    for (int e = 1; e < 8; e++) if (g[e] > g[i0]) i0 = e;
    int i1 = (i0 == 0) ? 1 : 0;
    for (int e = 0; e < 8; e++) if (e != i0 && g[e] > g[i1]) i1 = e;
    float w0 = 1.f / (1.f + expf(g[i1] - g[i0]));
    pe[2 * b] = i0; pe[2 * b + 1] = i1;
    pw[2 * b] = w0; pw[2 * b + 1] = 1.f - w0;
  }
}

// ---------------------------------------------------------------------------
__global__ __launch_bounds__(768) void mk_conv(const float* __restrict__ xz,
                                               const float* __restrict__ cw,
                                               const float* __restrict__ cb,
                                               const int* __restrict__ pe,
                                               float* __restrict__ xc)
{
  int blk = blockIdx.x;
  int p = blk >> 8, t = blk & 255;
  int e = pe[p];
  int h = t >> 4, w = t & 15;
  int c = threadIdx.x;
  const float* wp = cw + ((long)e * DIMC + c) * 9;
  float acc = cb[e * DIMC + c];
#pragma unroll
  for (int dh = 0; dh < 3; dh++) {
    int hh = h + dh - 1;
    if (hh < 0 || hh > 15) continue;
#pragma unroll
    for (int dw = 0; dw < 3; dw++) {
      int ww = w + dw - 1;
      if (ww < 0 || ww > 15) continue;
      acc += xz[((long)p * LTOK + hh * 16 + ww) * 1536 + c] * wp[dh * 3 + dw];
    }
  }
  xc[((long)p * LTOK + t) * DIMC + c] = acc / (1.f + expf(-acc));
}

// scan index s -> row-major token, per direction
__device__ __forceinline__ int tmap(int dir, int s) {
  if (dir == 0) return s;
  if (dir == 1) return 255 - s;
  if (dir == 2) return ((s & 15) << 4) | (s >> 4);
  int u = 255 - s;
  return ((u & 15) << 4) | (u >> 4);
}

// ---------------------------------------------------------------------------
// dblm[p][m][dir*6+j] = xc[p,m,:] . xproj[e,dir,j,:]
// grid: 32 p x 4 token-quarters; 256 threads = 64 tokens x 4 dirs.
// ---------------------------------------------------------------------------
__global__ __launch_bounds__(256) void mk_dbl(const float* __restrict__ xc,
                                              const float* __restrict__ xproj,
                                              const int* __restrict__ pe,
                                              float* __restrict__ dblm)
{
  int p = blockIdx.x >> 2, q = blockIdx.x & 3;
  int e = pe[p];
  int tl = threadIdx.x & 63;
  int dir = threadIdx.x >> 6;
  int m = q * 64 + tl;
  const float* xr = xc + ((long)p * LTOK + m) * DIMC;
  const float* wbase = xproj + (long)(e * 4 + dir) * 6 * DIMC;
  float s[6] = {0.f, 0.f, 0.f, 0.f, 0.f, 0.f};
  for (int c = 0; c < DIMC; c += 4) {
    float4 xv = *(const float4*)(xr + c);
#pragma unroll
    for (int j = 0; j < 6; j++) {
      float4 wv = *(const float4*)(wbase + j * DIMC + c);
      s[j] += xv.x * wv.x + xv.y * wv.y + xv.z * wv.z + xv.w * wv.w;
    }
  }
  float* o = dblm + ((long)p * LTOK + m) * 24 + dir * 6;
#pragma unroll
  for (int j = 0; j < 6; j++) o[j] = s[j];
}

// ---------------------------------------------------------------------------
// Selective scan v2: grid = (p, dir, channel-half) = 256 blocks x 384 thr.
// t chunked by 8: batch transcendentals + loads, serial part = 8 fmas.
// ---------------------------------------------------------------------------
__global__ __launch_bounds__(384) void mk_scan2(const float* __restrict__ xc,
                                                const float* __restrict__ dblm,
                                                const float* __restrict__ dtw,
                                                const float* __restrict__ dtb,
                                                const float* __restrict__ Alog,
                                                const float* __restrict__ Dp,
                                                const int* __restrict__ pe,
                                                float* __restrict__ yac)
{
  int blk = blockIdx.x;
  int p = blk >> 3, dir = (blk >> 1) & 3, half = blk & 1;
  int e = pe[p];
  __shared__ float dblS[256][6];
  int tid = threadIdx.x;
  for (int i = tid; i < 1536; i += 384) {
    int t = i / 6, j = i - t * 6;
    dblS[t][j] = dblm[((long)p * LTOK + tmap(dir, t)) * 24 + dir * 6 + j];
  }
  __syncthreads();

  int d = half * 384 + tid;
  const float* xcp = xc + (long)p * LTOK * DIMC;
  float* yp = yac + (long)p * LTOK * DIMC;
  long pb = (long)(e * 4 + dir) * DIMC + d;
  float4 wv = *(const float4*)(dtw + pb * 4);
  float bdt = dtb[pb];
  float Ad = -expf(Alog[pb]);
  float Dd = Dp[pb];
  float h = 0.f;
  for (int tb = 0; tb < 256; tb += 8) {
    float dec[8], u[8], cc[8], dd[8];
    int mm[8];
#pragma unroll
    for (int i = 0; i < 8; i++) {
      int t = tb + i;
      int m = tmap(dir, t);
      mm[i] = m;
      float xr = wv.x * dblS[t][0] + wv.y * dblS[t][1] + wv.z * dblS[t][2] +
                 wv.w * dblS[t][3] + bdt;
      float dt = fmaxf(xr, 0.f) + log1pf(expf(-fabsf(xr)));  // softplus
      float xv = xcp[(long)m * DIMC + d];
      dec[i] = expf(dt * Ad);
      u[i] = dt * xv * dblS[t][4];
      cc[i] = dblS[t][5];
      dd[i] = Dd * xv;
    }
#pragma unroll
    for (int i = 0; i < 8; i++) {
      h = dec[i] * h + u[i];
      atomicAdd(&yp[(long)mm[i] * DIMC + d], h * cc[i] + dd[i]);
    }
  }
}

// ---------------------------------------------------------------------------
__global__ __launch_bounds__(768) void mk_lnfin(const float* __restrict__ yac,
                                                const float* __restrict__ xz,
                                                const float* __restrict__ lns,
                                                const float* __restrict__ lnb,
                                                const int* __restrict__ pe,
                                                float* __restrict__ eo)
{
  int p = blockIdx.x;
  int e = pe[p];
  int tid = threadIdx.x;
  int wid = tid >> 6, lane = tid & 63;
  float ls[12], lb[12], acc[12];
#pragma unroll
  for (int i = 0; i < 12; i++) {
    int d = i * 64 + lane;
    ls[i] = lns[e * DIMC + d];
    lb[i] = lnb[e * DIMC + d];
    acc[i] = 0.f;
  }
  for (int t = wid; t < 256; t += 12) {
    const float* yr = yac + ((long)p * LTOK + t) * DIMC;
    const float* zr = xz + ((long)p * LTOK + t) * 1536 + DIMC;
    float v[12];
    float s = 0.f;
#pragma unroll
    for (int i = 0; i < 12; i++) { v[i] = yr[i * 64 + lane]; s += v[i]; }
#pragma unroll
    for (int o = 32; o; o >>= 1) s += __shfl_xor(s, o, 64);
    float mu = s * (1.f / 768.f);
    float sq = 0.f;
#pragma unroll
    for (int i = 0; i < 12; i++) { float dlt = v[i] - mu; sq += dlt * dlt; }
#pragma unroll
    for (int o = 32; o; o >>= 1) sq += __shfl_xor(sq, o, 64);
    float rs = rsqrtf(sq * (1.f / 768.f) + 1e-5f);
#pragma unroll
    for (int i = 0; i < 12; i++) {
      float y = (v[i] - mu) * rs * ls[i] + lb[i];
      float z = zr[i * 64 + lane];
      y *= z / (1.f + expf(-z));
      acc[i] += y;
    }
  }
  __shared__ float sacc[768];
  sacc[tid] = 0.f;
  __syncthreads();
#pragma unroll
  for (int i = 0; i < 12; i++) atomicAdd(&sacc[i * 64 + lane], acc[i]);
  __syncthreads();
  eo[(long)p * DIMC + tid] = sacc[tid] * (1.f / 256.f);
}

__global__ __launch_bounds__(768) void mk_out(const float* __restrict__ eo,
                                              const float* __restrict__ pw,
                                              float* __restrict__ out)
{
  int b = blockIdx.x, d = threadIdx.x;
  float v = pw[2 * b] * eo[(long)(2 * b) * DIMC + d] +
            pw[2 * b + 1] * eo[(long)(2 * b + 1) * DIMC + d];
  out[b * DIMC + d] = v;
}

// ---------------------------------------------------------------------------
static inline void cast_b(hipStream_t s, const float* in, ushortt* o, long n) {
  mk_cast<<<(int)((n + 1023) / 1024), 256, 0, s>>>(in, o, n);
}

static inline void mfma_gemm(hipStream_t stream, const ushortt* A, const ushortt* B,
                             const float* bias, float* C, int M, int N, int K,
                             int lda, int ldb, int ldc, int Z,
                             long sA, long sB, long sC, long sBias, const int* pairExp)
{
  int tilesM = M >> 7, tilesN = N >> 7;
  mk_mfma<<<dim3(tilesM * tilesN, Z), 256, 0, stream>>>(
      A, B, bias, C, K, lda, ldb, ldc, sA, sB, sC, sBias, pairExp, tilesN);
}

extern "C" void kernel_launch(void* const* d_in, const int* in_sizes, int n_in,
                              void* d_out, int out_size, void* d_ws, size_t ws_size,
                              hipStream_t stream)
{
  const float* x        = (const float*)d_in[0];
  const float* sa_in_w  = (const float*)d_in[1];
  const float* sa_in_b  = (const float*)d_in[2];
  const float* sa_out_w = (const float*)d_in[3];
  const float* sa_out_b = (const float*)d_in[4];
  const float* ca_in_w  = (const float*)d_in[5];
  const float* ca_in_b  = (const float*)d_in[6];
  const float* eq       = (const float*)d_in[7];
  const float* e_in_w   = (const float*)d_in[8];
  const float* e_in_b   = (const float*)d_in[9];
  const float* e_conv_w = (const float*)d_in[10];
  const float* e_conv_b = (const float*)d_in[11];
  const float* e_xproj  = (const float*)d_in[12];
  const float* e_dtw    = (const float*)d_in[13];
  const float* e_dtb    = (const float*)d_in[14];
  const float* e_Alog   = (const float*)d_in[15];
  const float* e_D      = (const float*)d_in[16];
  const float* e_lns    = (const float*)d_in[17];
  const float* e_lnb    = (const float*)d_in[18];
  float* out = (float*)d_out;

  float* ws = (float*)d_ws;
  // ---- attention phase ----
  float*   qkv    = ws + 0;                         // 9,437,184
  float*   scores = ws + 9437184;                   // 8,388,608
  float*   ctxa   = ws + 17825792;                  // 3,145,728 (ends 20,971,520)
  ushortt* xb     = (ushortt*)(ws + 20971520);      // 3,145,728 bf16 (1,572,864 slots)
  ushortt* wqkv_b = (ushortt*)(ws + 22544384);      // 1,769,472 bf16 (884,736 slots); dead after qkv
  ushortt* saow_b = (ushortt*)(ws + 22544384);      // overlay wqkv_b: 589,824 bf16
  ushortt* caw_b  = (ushortt*)(ws + 22839296);      // 589,824 bf16
  ushortt* ctxa_b = (ushortt*)(ws + 9437184);       // overlay scores (dead after av)
  float*   ctx    = ws + 0;                         // overlay qkv (dead): 3,145,728
  ushortt* ctx_b  = (ushortt*)(ws + 3145728);       // 3,145,728 bf16
  float*   q2     = ws + 4718592;                   // 3,145,728 (ends 7,864,320)
  // ---- persistent smalls ----
  float*   k2     = ws + 25165824;                  // 6,144
  int*     pe     = (int*)(ws + 25171968);          // 32
  float*   pw     = ws + 25172000;                  // 32
  float*   eo     = ws + 25172032;                  // 24,576 (ends 25,196,608)
  float*   dblm   = ws + 25196608;                  // 196,608 (ends 25,393,216 = 101.6MB)
  // ---- expert phase (attention regions dead) ----
  float*   xz     = ws + 0;                         // 12,582,912
  ushortt* ew_b   = (ushortt*)(ws + 12582912);      // 9,437,184 bf16; dead after xz GEMM
  float*   xc     = ws + 12582912;                  // 6,291,456 (conv writes after)
  float*   yac    = ws + 18874368;                  // 6,291,456 (memset after conv; xb dead)

  const float scale = 0.10206207261596577f;

  // casts for qkv GEMM
  cast_b(stream, x, xb, 3145728);
  cast_b(stream, sa_in_w, wqkv_b, 1769472);
  // 1. qkv = x @ sa_in_w^T + b  (4096 x 2304 x 768, MFMA)
  mfma_gemm(stream, xb, wqkv_b, sa_in_b, qkv, 4096, 2304, 768, 768, 768, 2304,
            1, 0, 0, 0, 0, nullptr);
  // 2. scores[b,h] = q @ k^T  (256x256x96, Z=128, fp32)
  mk_gemm<<<dim3(16, 128), 256, 0, stream>>>(qkv, qkv + 768, nullptr, scores,
      256, 256, 96, 2304, 2304, 256, 8, 589824, 96, 589824, 96, 524288, 65536, 1, 4);
  // 3. softmax
  mk_softmax<<<8192, 256, 0, stream>>>(scores, scale);
  // 4. ctxa[b,h] = att @ v  (256x96x256, NN, Z=128, fp32)
  mk_gemm<<<dim3(8, 128), 256, 0, stream>>>(scores, qkv + 1536, nullptr, ctxa,
      256, 96, 256, 256, 2304, 768, 8, 524288, 65536, 589824, 96, 196608, 96, 0, 2);
  // 5. ctx = ctxa @ sa_out_w^T + b  (4096x768x768, MFMA)
  cast_b(stream, ctxa, ctxa_b, 3145728);
  cast_b(stream, sa_out_w, saow_b, 589824);
  mfma_gemm(stream, ctxa_b, saow_b, sa_out_b, ctx, 4096, 768, 768, 768, 768, 768,
            1, 0, 0, 0, 0, nullptr);
  // 6. q2 = ctx @ ca_in_w[:768]^T + b  (MFMA)
  cast_b(stream, ctx, ctx_b, 3145728);
  cast_b(stream, ca_in_w, caw_b, 589824);
  mfma_gemm(stream, ctx_b, caw_b, ca_in_b, q2, 4096, 768, 768, 768, 768, 768,
            1, 0, 0, 0, 0, nullptr);
  // 7. k2 = eq @ ca_in_w[768:]^T + b  (8x768x768, fp32)
  mk_gemm<<<dim3(12, 1), 256, 0, stream>>>(eq, ca_in_w + 589824, ca_in_b + 768, k2,
      8, 768, 768, 768, 768, 768, 1, 0, 0, 0, 0, 0, 0, 1, 12);
  // 8. gate
  mk_gate<<<16, 256, 0, stream>>>(q2, k2, pe, pw);
  // 9. xz[p] = x[b] @ e_in_w[e]^T + b  (256x1536x768, Z=32, MFMA pair mode)
  cast_b(stream, e_in_w, ew_b, 9437184);
  mfma_gemm(stream, xb, ew_b, e_in_b, xz, 256, 1536, 768, 768, 768, 1536,
            32, 196608, 1179648, 393216, 1536, pe);
  // 10. depthwise conv + SiLU
  mk_conv<<<32 * 256, 768, 0, stream>>>(xz, e_conv_w, e_conv_b, pe, xc);
  // 11. dblm projections (parallel)
  mk_dbl<<<128, 256, 0, stream>>>(xc, e_xproj, pe, dblm);
  // 12. zero accumulator + selective scans
  hipMemsetAsync(yac, 0, (size_t)6291456 * sizeof(float), stream);
  mk_scan2<<<256, 384, 0, stream>>>(xc, dblm, e_dtw, e_dtb, e_Alog, e_D, pe, yac);
  // 13. LN + silu(z) + token mean
  mk_lnfin<<<32, 768, 0, stream>>>(yac, xz, e_lns, e_lnb, pe, eo);
  // 14. weighted top-2 combine
  mk_out<<<16, 768, 0, stream>>>(eo, pw, out);

  (void)in_sizes; (void)n_in; (void)out_size; (void)ws_size;
}

// Round 5
// 772.175 us; speedup vs baseline: 2.0379x; 1.2032x over previous
//
#include <hip/hip_runtime.h>
#include <hip/hip_bf16.h>

// MoEFSCIL: B=16, H=W=16, L=256, DIM=768, NH=8, HD=96, NEXP=8, TOPK=2.
// fp32 in/out. Big GEMMs in bf16 MFMA (16x16x32), attention + scan fp32.

#define LTOK 256
#define DIMC 768

typedef unsigned short ushortt;
typedef __attribute__((ext_vector_type(8))) short bf16x8;
typedef __attribute__((ext_vector_type(4))) float f32x4;

// round-to-nearest-even fp32 -> bf16 bits
__device__ __forceinline__ ushortt f2b(float f) {
  union { float f; unsigned u; } c; c.f = f;
  unsigned r = (c.u + 0x7FFFu + ((c.u >> 16) & 1u)) >> 16;
  return (ushortt)r;
}

// ---------------------------------------------------------------------------
__global__ __launch_bounds__(256) void mk_cast(const float* __restrict__ in,
                                               ushortt* __restrict__ outp, long n)
{
  long i = ((long)blockIdx.x * 256 + threadIdx.x) * 4;
  if (i + 3 < n) {
    float4 v = *(const float4*)(in + i);
    ushort4 o;
    o.x = f2b(v.x); o.y = f2b(v.y); o.z = f2b(v.z); o.w = f2b(v.w);
    *(ushort4*)(outp + i) = o;
  }
}

// ---------------------------------------------------------------------------
// bf16 MFMA GEMM: C[z](M,N) = A[z](M,K) @ B[z](N,K)^T + bias. fp32 out.
// ---------------------------------------------------------------------------
__global__ __launch_bounds__(256) void mk_mfma(
    const ushortt* __restrict__ A, const ushortt* __restrict__ B,
    const float* __restrict__ bias, float* __restrict__ C,
    int K, int lda, int ldb, int ldc,
    long sA, long sB, long sC, long sBias,
    const int* __restrict__ pairExp, int tilesN)
{
  int z = blockIdx.y;
  long aoff = 0, boff = 0, coff = 0, biasoff = 0;
  if (pairExp) {
    int e = pairExp[z];
    aoff = (long)(z >> 1) * sA; boff = (long)e * sB;
    coff = (long)z * sC; biasoff = (long)e * sBias;
  }
  int tile = blockIdx.x;
  int tm = tile / tilesN, tn = tile - tm * tilesN;
  long m0 = (long)tm << 7, n0 = (long)tn << 7;

  __shared__ ushortt As[128][40];
  __shared__ ushortt Bs[128][40];

  int tid = threadIdx.x;
  int lane = tid & 63, wvi = tid >> 6;
  int wr = wvi >> 1, wc = wvi & 1;
  int lm = lane & 15, lg = lane >> 4;

  f32x4 zero4 = {0.f, 0.f, 0.f, 0.f};
  f32x4 acc[4][4];
#pragma unroll
  for (int i = 0; i < 4; i++)
#pragma unroll
    for (int j = 0; j < 4; j++) acc[i][j] = zero4;

  const ushortt* Ab = A + aoff;
  const ushortt* Bb = B + boff;

  for (int k0 = 0; k0 < K; k0 += 32) {
#pragma unroll
    for (int h = 0; h < 2; h++) {
      int q = tid + h * 256;
      int row = q >> 2, ck = (q & 3) << 3;
      *(uint4*)&As[row][ck] = *(const uint4*)(Ab + (m0 + row) * lda + k0 + ck);
      *(uint4*)&Bs[row][ck] = *(const uint4*)(Bb + (n0 + row) * ldb + k0 + ck);
    }
    __syncthreads();
    bf16x8 af[4], bfr[4];
#pragma unroll
    for (int i = 0; i < 4; i++)
      af[i] = *(const bf16x8*)&As[wr * 64 + i * 16 + lm][lg << 3];
#pragma unroll
    for (int j = 0; j < 4; j++)
      bfr[j] = *(const bf16x8*)&Bs[wc * 64 + j * 16 + lm][lg << 3];
#pragma unroll
    for (int i = 0; i < 4; i++)
#pragma unroll
      for (int j = 0; j < 4; j++)
        acc[i][j] = __builtin_amdgcn_mfma_f32_16x16x32_bf16(af[i], bfr[j], acc[i][j], 0, 0, 0);
    __syncthreads();
  }

#pragma unroll
  for (int mt = 0; mt < 4; mt++) {
#pragma unroll
    for (int nt = 0; nt < 4; nt++) {
      long grow = m0 + wr * 64 + mt * 16 + lg * 4;
      long gcol = n0 + wc * 64 + nt * 16 + lm;
      float bv = bias ? bias[biasoff + gcol] : 0.f;
#pragma unroll
      for (int r = 0; r < 4; r++)
        C[coff + (grow + r) * ldc + gcol] = acc[mt][nt][r] + bv;
    }
  }
}

// ---------------------------------------------------------------------------
// fp32 batched GEMM (attention + k2)
// ---------------------------------------------------------------------------
__global__ __launch_bounds__(256) void mk_gemm(
    const float* __restrict__ A, const float* __restrict__ B,
    const float* __restrict__ bias, float* __restrict__ C,
    int M, int N, int K, int lda, int ldb, int ldc,
    int zdiv,
    long sA1, long sA2, long sB1, long sB2, long sC1, long sC2,
    int bIsNT, int tilesN)
{
  int z = blockIdx.y;
  int z1 = z / zdiv, z2 = z - z1 * zdiv;
  const float* Ab = A + (long)z1 * sA1 + (long)z2 * sA2;
  const float* Bb = B + (long)z1 * sB1 + (long)z2 * sB2;
  float* Cb = C + (long)z1 * sC1 + (long)z2 * sC2;

  int tile = blockIdx.x;
  int tm = tile / tilesN, tn = tile - tm * tilesN;
  int m0 = tm << 6, n0 = tn << 6;

  __shared__ float As[16][68];
  __shared__ float Bs[16][68];

  int tid = threadIdx.x;
  int tx = tid & 15, ty = tid >> 4;
  int lrow = tid >> 2;
  int lk = (tid & 3) << 2;
  int bkk = tid >> 4;
  int bnn = (tid & 15) << 2;

  float acc[4][4];
#pragma unroll
  for (int i = 0; i < 4; i++)
#pragma unroll
    for (int j = 0; j < 4; j++) acc[i][j] = 0.f;

  for (int k0 = 0; k0 < K; k0 += 16) {
    {
      int gm = m0 + lrow;
      float4 v = {0.f, 0.f, 0.f, 0.f};
      if (gm < M) v = *(const float4*)(Ab + (long)gm * lda + (k0 + lk));
      As[lk + 0][lrow] = v.x; As[lk + 1][lrow] = v.y;
      As[lk + 2][lrow] = v.z; As[lk + 3][lrow] = v.w;
    }
    if (bIsNT) {
      int gn = n0 + lrow;
      float4 v = {0.f, 0.f, 0.f, 0.f};
      if (gn < N) v = *(const float4*)(Bb + (long)gn * ldb + (k0 + lk));
      Bs[lk + 0][lrow] = v.x; Bs[lk + 1][lrow] = v.y;
      Bs[lk + 2][lrow] = v.z; Bs[lk + 3][lrow] = v.w;
    } else {
      int gn = n0 + bnn;
      float4 v = {0.f, 0.f, 0.f, 0.f};
      if (gn + 3 < N) {
        v = *(const float4*)(Bb + (long)(k0 + bkk) * ldb + gn);
      } else {
        float t0 = (gn + 0 < N) ? Bb[(long)(k0 + bkk) * ldb + gn + 0] : 0.f;
        float t1 = (gn + 1 < N) ? Bb[(long)(k0 + bkk) * ldb + gn + 1] : 0.f;
        float t2 = (gn + 2 < N) ? Bb[(long)(k0 + bkk) * ldb + gn + 2] : 0.f;
        float t3 = (gn + 3 < N) ? Bb[(long)(k0 + bkk) * ldb + gn + 3] : 0.f;
        v.x = t0; v.y = t1; v.z = t2; v.w = t3;
      }
      *(float4*)&Bs[bkk][bnn] = v;
    }
    __syncthreads();
#pragma unroll
    for (int kk = 0; kk < 16; kk++) {
      float4 a = *(const float4*)&As[kk][ty << 2];
      float4 b = *(const float4*)&Bs[kk][tx << 2];
      acc[0][0] += a.x * b.x; acc[0][1] += a.x * b.y; acc[0][2] += a.x * b.z; acc[0][3] += a.x * b.w;
      acc[1][0] += a.y * b.x; acc[1][1] += a.y * b.y; acc[1][2] += a.y * b.z; acc[1][3] += a.y * b.w;
      acc[2][0] += a.z * b.x; acc[2][1] += a.z * b.y; acc[2][2] += a.z * b.z; acc[2][3] += a.z * b.w;
      acc[3][0] += a.w * b.x; acc[3][1] += a.w * b.y; acc[3][2] += a.w * b.z; acc[3][3] += a.w * b.w;
    }
    __syncthreads();
  }

#pragma unroll
  for (int i = 0; i < 4; i++) {
    int gm = m0 + (ty << 2) + i;
    if (gm >= M) continue;
#pragma unroll
    for (int j = 0; j < 4; j++) {
      int gn = n0 + (tx << 2) + j;
      if (gn >= N) continue;
      float v = acc[i][j];
      if (bias) v += bias[gn];
      Cb[(long)gm * ldc + gn] = v;
    }
  }
}

// ---------------------------------------------------------------------------
__global__ __launch_bounds__(256) void mk_softmax(float* __restrict__ scores, float scale)
{
  int row = (blockIdx.x << 2) + (threadIdx.x >> 6);
  int lane = threadIdx.x & 63;
  float* p = scores + (long)row * 256 + (lane << 2);
  float4 v = *(const float4*)p;
  float m = fmaxf(fmaxf(v.x, v.y), fmaxf(v.z, v.w));
#pragma unroll
  for (int o = 32; o; o >>= 1) m = fmaxf(m, __shfl_xor(m, o, 64));
  v.x = expf(scale * (v.x - m));
  v.y = expf(scale * (v.y - m));
  v.z = expf(scale * (v.z - m));
  v.w = expf(scale * (v.w - m));
  float s = v.x + v.y + v.z + v.w;
#pragma unroll
  for (int o = 32; o; o >>= 1) s += __shfl_xor(s, o, 64);
  float r = 1.f / s;
  v.x *= r; v.y *= r; v.z *= r; v.w *= r;
  *(float4*)p = v;
}

// ---------------------------------------------------------------------------
// Gate stage 1: grid (b*16 + slice) = 256 blocks, 256 thr (4 waves).
// Wave = one token; lane = h*8+e. k2 in LDS padded: addr e*808+h*100+j
// -> per-access 2 lanes/bank (free). Softmax over e via shfl 1,2,4;
// h-sum via shfl 8,16,32; per-block atomicAdd into gacc[b][e].
// ---------------------------------------------------------------------------
__global__ __launch_bounds__(256) void mk_gates(const float* __restrict__ q2,
                                                const float* __restrict__ k2,
                                                float* __restrict__ gacc)
{
  __shared__ float k2p[8 * 808];
  int b = blockIdx.x >> 4, q = blockIdx.x & 15;
  for (int i = threadIdx.x; i < 6144; i += 256) {
    int e = i / 768, rem = i - e * 768;
    int h = rem / 96, j = rem - h * 96;
    k2p[e * 808 + h * 100 + j] = k2[i];
  }
  __syncthreads();
  const float scale = 0.10206207261596577f;  // 1/sqrt(96)
  int wid = threadIdx.x >> 6, lane = threadIdx.x & 63;
  int h = lane >> 3, e = lane & 7;
  const float* kp = &k2p[e * 808 + h * 100];
  float accL = 0.f;
#pragma unroll
  for (int ti = 0; ti < 4; ti++) {
    int l = q * 16 + wid * 4 + ti;
    const float* qh = q2 + ((long)b * LTOK + l) * DIMC + h * 96;
    float sum = 0.f;
#pragma unroll
    for (int j = 0; j < 96; j += 4) {
      float4 qv = *(const float4*)(qh + j);
      float4 kv = *(const float4*)(kp + j);
      sum += qv.x * kv.x + qv.y * kv.y + qv.z * kv.z + qv.w * kv.w;
    }
    float s = sum * scale;
    float mx = s;
#pragma unroll
    for (int o = 1; o <= 4; o <<= 1) mx = fmaxf(mx, __shfl_xor(mx, o, 64));
    float ex = expf(s - mx);
    float se = ex;
#pragma unroll
    for (int o = 1; o <= 4; o <<= 1) se += __shfl_xor(se, o, 64);
    accL += ex / se;
  }
#pragma unroll
  for (int o = 8; o <= 32; o <<= 1) accL += __shfl_xor(accL, o, 64);
  __shared__ float red[4][8];
  if (lane < 8) red[wid][lane] = accL;
  __syncthreads();
  if (threadIdx.x < 8) {
    float v = red[0][threadIdx.x] + red[1][threadIdx.x] +
              red[2][threadIdx.x] + red[3][threadIdx.x];
    atomicAdd(&gacc[b * 8 + threadIdx.x], v);
  }
}

// Gate stage 2: tiny finisher (softmax over 8, top-2).
__global__ __launch_bounds__(64) void mk_gatetop(const float* __restrict__ gacc,
                                                 int* __restrict__ pe,
                                                 float* __restrict__ pw)
{
  int b = threadIdx.x;
  if (b >= 16) return;
  float g[8];
  for (int e = 0; e < 8; e++) g[e] = gacc[b * 8 + e] * (1.f / (8.f * 256.f));
  float mx = g[0];
  for (int e = 1; e < 8; e++) mx = fmaxf(mx, g[e]);
  float se = 0.f;
  for (int e = 0; e < 8; e++) { g[e] = expf(g[e] - mx); se += g[e]; }
  for (int e = 0; e < 8; e++) g[e] /= se;
  int i0 = 0;
  for (int e = 1; e < 8; e++) if (g[e] > g[i0]) i0 = e;
  int i1 = (i0 == 0) ? 1 : 0;
  for (int e = 0; e < 8; e++) if (e != i0 && g[e] > g[i1]) i1 = e;
  float w0 = 1.f / (1.f + expf(g[i1] - g[i0]));
  pe[2 * b] = i0; pe[2 * b + 1] = i1;
  pw[2 * b] = w0; pw[2 * b + 1] = 1.f - w0;
}

// ---------------------------------------------------------------------------
__global__ __launch_bounds__(768) void mk_conv(const float* __restrict__ xz,
                                               const float* __restrict__ cw,
                                               const float* __restrict__ cb,
                                               const int* __restrict__ pe,
                                               float* __restrict__ xc)
{
  int blk = blockIdx.x;
  int p = blk >> 8, t = blk & 255;
  int e = pe[p];
  int h = t >> 4, w = t & 15;
  int c = threadIdx.x;
  const float* wp = cw + ((long)e * DIMC + c) * 9;
  float acc = cb[e * DIMC + c];
#pragma unroll
  for (int dh = 0; dh < 3; dh++) {
    int hh = h + dh - 1;
    if (hh < 0 || hh > 15) continue;
#pragma unroll
    for (int dw = 0; dw < 3; dw++) {
      int ww = w + dw - 1;
      if (ww < 0 || ww > 15) continue;
      acc += xz[((long)p * LTOK + hh * 16 + ww) * 1536 + c] * wp[dh * 3 + dw];
    }
  }
  xc[((long)p * LTOK + t) * DIMC + c] = acc / (1.f + expf(-acc));
}

// scan index s -> row-major token, per direction
__device__ __forceinline__ int tmap(int dir, int s) {
  if (dir == 0) return s;
  if (dir == 1) return 255 - s;
  if (dir == 2) return ((s & 15) << 4) | (s >> 4);
  int u = 255 - s;
  return ((u & 15) << 4) | (u >> 4);
}

// ---------------------------------------------------------------------------
__global__ __launch_bounds__(256) void mk_dbl(const float* __restrict__ xc,
                                              const float* __restrict__ xproj,
                                              const int* __restrict__ pe,
                                              float* __restrict__ dblm)
{
  int p = blockIdx.x >> 2, q = blockIdx.x & 3;
  int e = pe[p];
  int tl = threadIdx.x & 63;
  int dir = threadIdx.x >> 6;
  int m = q * 64 + tl;
  const float* xr = xc + ((long)p * LTOK + m) * DIMC;
  const float* wbase = xproj + (long)(e * 4 + dir) * 6 * DIMC;
  float s[6] = {0.f, 0.f, 0.f, 0.f, 0.f, 0.f};
  for (int c = 0; c < DIMC; c += 4) {
    float4 xv = *(const float4*)(xr + c);
#pragma unroll
    for (int j = 0; j < 6; j++) {
      float4 wv = *(const float4*)(wbase + j * DIMC + c);
      s[j] += xv.x * wv.x + xv.y * wv.y + xv.z * wv.z + xv.w * wv.w;
    }
  }
  float* o = dblm + ((long)p * LTOK + m) * 24 + dir * 6;
#pragma unroll
  for (int j = 0; j < 6; j++) o[j] = s[j];
}

// ---------------------------------------------------------------------------
__global__ __launch_bounds__(384) void mk_scan2(const float* __restrict__ xc,
                                                const float* __restrict__ dblm,
                                                const float* __restrict__ dtw,
                                                const float* __restrict__ dtb,
                                                const float* __restrict__ Alog,
                                                const float* __restrict__ Dp,
                                                const int* __restrict__ pe,
                                                float* __restrict__ yac)
{
  int blk = blockIdx.x;
  int p = blk >> 3, dir = (blk >> 1) & 3, half = blk & 1;
  int e = pe[p];
  __shared__ float dblS[256][6];
  int tid = threadIdx.x;
  for (int i = tid; i < 1536; i += 384) {
    int t = i / 6, j = i - t * 6;
    dblS[t][j] = dblm[((long)p * LTOK + tmap(dir, t)) * 24 + dir * 6 + j];
  }
  __syncthreads();

  int d = half * 384 + tid;
  const float* xcp = xc + (long)p * LTOK * DIMC;
  float* yp = yac + (long)p * LTOK * DIMC;
  long pb = (long)(e * 4 + dir) * DIMC + d;
  float4 wv = *(const float4*)(dtw + pb * 4);
  float bdt = dtb[pb];
  float Ad = -expf(Alog[pb]);
  float Dd = Dp[pb];
  float h = 0.f;
  for (int tb = 0; tb < 256; tb += 8) {
    float dec[8], u[8], cc[8], dd[8];
    int mm[8];
#pragma unroll
    for (int i = 0; i < 8; i++) {
      int t = tb + i;
      int m = tmap(dir, t);
      mm[i] = m;
      float xr = wv.x * dblS[t][0] + wv.y * dblS[t][1] + wv.z * dblS[t][2] +
                 wv.w * dblS[t][3] + bdt;
      float dt = fmaxf(xr, 0.f) + log1pf(expf(-fabsf(xr)));  // softplus
      float xv = xcp[(long)m * DIMC + d];
      dec[i] = expf(dt * Ad);
      u[i] = dt * xv * dblS[t][4];
      cc[i] = dblS[t][5];
      dd[i] = Dd * xv;
    }
#pragma unroll
    for (int i = 0; i < 8; i++) {
      h = dec[i] * h + u[i];
      atomicAdd(&yp[(long)mm[i] * DIMC + d], h * cc[i] + dd[i]);
    }
  }
}

// ---------------------------------------------------------------------------
__global__ __launch_bounds__(768) void mk_lnfin(const float* __restrict__ yac,
                                                const float* __restrict__ xz,
                                                const float* __restrict__ lns,
                                                const float* __restrict__ lnb,
                                                const int* __restrict__ pe,
                                                float* __restrict__ eo)
{
  int p = blockIdx.x;
  int e = pe[p];
  int tid = threadIdx.x;
  int wid = tid >> 6, lane = tid & 63;
  float ls[12], lb[12], acc[12];
#pragma unroll
  for (int i = 0; i < 12; i++) {
    int d = i * 64 + lane;
    ls[i] = lns[e * DIMC + d];
    lb[i] = lnb[e * DIMC + d];
    acc[i] = 0.f;
  }
  for (int t = wid; t < 256; t += 12) {
    const float* yr = yac + ((long)p * LTOK + t) * DIMC;
    const float* zr = xz + ((long)p * LTOK + t) * 1536 + DIMC;
    float v[12];
    float s = 0.f;
#pragma unroll
    for (int i = 0; i < 12; i++) { v[i] = yr[i * 64 + lane]; s += v[i]; }
#pragma unroll
    for (int o = 32; o; o >>= 1) s += __shfl_xor(s, o, 64);
    float mu = s * (1.f / 768.f);
    float sq = 0.f;
#pragma unroll
    for (int i = 0; i < 12; i++) { float dlt = v[i] - mu; sq += dlt * dlt; }
#pragma unroll
    for (int o = 32; o; o >>= 1) sq += __shfl_xor(sq, o, 64);
    float rs = rsqrtf(sq * (1.f / 768.f) + 1e-5f);
#pragma unroll
    for (int i = 0; i < 12; i++) {
      float y = (v[i] - mu) * rs * ls[i] + lb[i];
      float z = zr[i * 64 + lane];
      y *= z / (1.f + expf(-z));
      acc[i] += y;
    }
  }
  __shared__ float sacc[768];
  sacc[tid] = 0.f;
  __syncthreads();
#pragma unroll
  for (int i = 0; i < 12; i++) atomicAdd(&sacc[i * 64 + lane], acc[i]);
  __syncthreads();
  eo[(long)p * DIMC + tid] = sacc[tid] * (1.f / 256.f);
}

__global__ __launch_bounds__(768) void mk_out(const float* __restrict__ eo,
                                              const float* __restrict__ pw,
                                              float* __restrict__ out)
{
  int b = blockIdx.x, d = threadIdx.x;
  float v = pw[2 * b] * eo[(long)(2 * b) * DIMC + d] +
            pw[2 * b + 1] * eo[(long)(2 * b + 1) * DIMC + d];
  out[b * DIMC + d] = v;
}

// ---------------------------------------------------------------------------
static inline void cast_b(hipStream_t s, const float* in, ushortt* o, long n) {
  mk_cast<<<(int)((n + 1023) / 1024), 256, 0, s>>>(in, o, n);
}

static inline void mfma_gemm(hipStream_t stream, const ushortt* A, const ushortt* B,
                             const float* bias, float* C, int M, int N, int K,
                             int lda, int ldb, int ldc, int Z,
                             long sA, long sB, long sC, long sBias, const int* pairExp)
{
  int tilesM = M >> 7, tilesN = N >> 7;
  mk_mfma<<<dim3(tilesM * tilesN, Z), 256, 0, stream>>>(
      A, B, bias, C, K, lda, ldb, ldc, sA, sB, sC, sBias, pairExp, tilesN);
}

extern "C" void kernel_launch(void* const* d_in, const int* in_sizes, int n_in,
                              void* d_out, int out_size, void* d_ws, size_t ws_size,
                              hipStream_t stream)
{
  const float* x        = (const float*)d_in[0];
  const float* sa_in_w  = (const float*)d_in[1];
  const float* sa_in_b  = (const float*)d_in[2];
  const float* sa_out_w = (const float*)d_in[3];
  const float* sa_out_b = (const float*)d_in[4];
  const float* ca_in_w  = (const float*)d_in[5];
  const float* ca_in_b  = (const float*)d_in[6];
  const float* eq       = (const float*)d_in[7];
  const float* e_in_w   = (const float*)d_in[8];
  const float* e_in_b   = (const float*)d_in[9];
  const float* e_conv_w = (const float*)d_in[10];
  const float* e_conv_b = (const float*)d_in[11];
  const float* e_xproj  = (const float*)d_in[12];
  const float* e_dtw    = (const float*)d_in[13];
  const float* e_dtb    = (const float*)d_in[14];
  const float* e_Alog   = (const float*)d_in[15];
  const float* e_D      = (const float*)d_in[16];
  const float* e_lns    = (const float*)d_in[17];
  const float* e_lnb    = (const float*)d_in[18];
  float* out = (float*)d_out;

  float* ws = (float*)d_ws;
  // ---- attention phase ----
  float*   qkv    = ws + 0;                         // 9,437,184
  float*   scores = ws + 9437184;                   // 8,388,608
  float*   ctxa   = ws + 17825792;                  // 3,145,728 (ends 20,971,520)
  ushortt* xb     = (ushortt*)(ws + 20971520);      // 1,572,864 fl slots
  ushortt* wqkv_b = (ushortt*)(ws + 22544384);      // dead after qkv
  ushortt* saow_b = (ushortt*)(ws + 22544384);      // overlay wqkv_b
  ushortt* caw_b  = (ushortt*)(ws + 22839296);
  ushortt* ctxa_b = (ushortt*)(ws + 9437184);       // overlay scores (dead)
  float*   ctx    = ws + 0;                         // overlay qkv (dead)
  ushortt* ctx_b  = (ushortt*)(ws + 3145728);
  float*   q2     = ws + 4718592;                   // ends 7,864,320
  // ---- persistent smalls ----
  float*   k2     = ws + 25165824;                  // 6,144
  int*     pe     = (int*)(ws + 25171968);          // 32
  float*   pw     = ws + 25172000;                  // 32
  float*   eo     = ws + 25172032;                  // 24,576
  float*   dblm   = ws + 25196608;                  // 196,608 (ends 25,393,216)
  float*   gacc   = ws + 25393216;                  // 128 (gate accumulator)
  // ---- expert phase ----
  float*   xz     = ws + 0;                         // 12,582,912
  ushortt* ew_b   = (ushortt*)(ws + 12582912);      // dead after xz GEMM
  float*   xc     = ws + 12582912;                  // 6,291,456
  float*   yac    = ws + 18874368;                  // 6,291,456

  const float scale = 0.10206207261596577f;

  cast_b(stream, x, xb, 3145728);
  cast_b(stream, sa_in_w, wqkv_b, 1769472);
  // 1. qkv = x @ sa_in_w^T + b  (4096 x 2304 x 768, MFMA)
  mfma_gemm(stream, xb, wqkv_b, sa_in_b, qkv, 4096, 2304, 768, 768, 768, 2304,
            1, 0, 0, 0, 0, nullptr);
  // 2. scores[b,h] = q @ k^T  (256x256x96, Z=128, fp32)
  mk_gemm<<<dim3(16, 128), 256, 0, stream>>>(qkv, qkv + 768, nullptr, scores,
      256, 256, 96, 2304, 2304, 256, 8, 589824, 96, 589824, 96, 524288, 65536, 1, 4);
  // 3. softmax
  mk_softmax<<<8192, 256, 0, stream>>>(scores, scale);
  // 4. ctxa[b,h] = att @ v  (256x96x256, NN, Z=128, fp32)
  mk_gemm<<<dim3(8, 128), 256, 0, stream>>>(scores, qkv + 1536, nullptr, ctxa,
      256, 96, 256, 256, 2304, 768, 8, 524288, 65536, 589824, 96, 196608, 96, 0, 2);
  // 5. ctx = ctxa @ sa_out_w^T + b  (4096x768x768, MFMA)
  cast_b(stream, ctxa, ctxa_b, 3145728);
  cast_b(stream, sa_out_w, saow_b, 589824);
  mfma_gemm(stream, ctxa_b, saow_b, sa_out_b, ctx, 4096, 768, 768, 768, 768, 768,
            1, 0, 0, 0, 0, nullptr);
  // 6. q2 = ctx @ ca_in_w[:768]^T + b  (MFMA)
  cast_b(stream, ctx, ctx_b, 3145728);
  cast_b(stream, ca_in_w, caw_b, 589824);
  mfma_gemm(stream, ctx_b, caw_b, ca_in_b, q2, 4096, 768, 768, 768, 768, 768,
            1, 0, 0, 0, 0, nullptr);
  // 7. k2 = eq @ ca_in_w[768:]^T + b  (8x768x768, fp32)
  mk_gemm<<<dim3(12, 1), 256, 0, stream>>>(eq, ca_in_w + 589824, ca_in_b + 768, k2,
      8, 768, 768, 768, 768, 768, 1, 0, 0, 0, 0, 0, 0, 1, 12);
  // 8. gate: zero acc, parallel scores, tiny top-2
  hipMemsetAsync(gacc, 0, 128 * sizeof(float), stream);
  mk_gates<<<256, 256, 0, stream>>>(q2, k2, gacc);
  mk_gatetop<<<1, 64, 0, stream>>>(gacc, pe, pw);
  // 9. xz[p] = x[b] @ e_in_w[e]^T + b  (256x1536x768, Z=32, MFMA pair mode)
  cast_b(stream, e_in_w, ew_b, 9437184);
  mfma_gemm(stream, xb, ew_b, e_in_b, xz, 256, 1536, 768, 768, 768, 1536,
            32, 196608, 1179648, 393216, 1536, pe);
  // 10. depthwise conv + SiLU
  mk_conv<<<32 * 256, 768, 0, stream>>>(xz, e_conv_w, e_conv_b, pe, xc);
  // 11. dblm projections
  mk_dbl<<<128, 256, 0, stream>>>(xc, e_xproj, pe, dblm);
  // 12. zero accumulator + selective scans
  hipMemsetAsync(yac, 0, (size_t)6291456 * sizeof(float), stream);
  mk_scan2<<<256, 384, 0, stream>>>(xc, dblm, e_dtw, e_dtb, e_Alog, e_D, pe, yac);
  // 13. LN + silu(z) + token mean
  mk_lnfin<<<32, 768, 0, stream>>>(yac, xz, e_lns, e_lnb, pe, eo);
  // 14. weighted top-2 combine
  mk_out<<<16, 768, 0, stream>>>(eo, pw, out);

  (void)in_sizes; (void)n_in; (void)out_size; (void)ws_size;
}